// Round 1
// baseline (1275.811 us; speedup 1.0000x reference)
//
#include <hip/hip_runtime.h>
#include <math.h>

#define DIMC 256
#define DST 16
#define DIN 512
#define DTR 16
#define BB 2
#define HH 48
#define WW 48
#define LL (HH*WW)      // 2304
#define MM (BB*LL)      // 4608

__device__ __forceinline__ float silu_f(float a){ return a / (1.f + expf(-a)); }
__device__ __forceinline__ float softplus_f(float a){ return a > 20.f ? a : log1pf(expf(a)); }

// ---------------- LayerNorm over channels: x[B,C,H,W] -> xn[B,L,C] ----------------
__global__ __launch_bounds__(256) void ln_kernel(const float* __restrict__ x,
    const float* __restrict__ w, const float* __restrict__ bgain,
    float* __restrict__ xn) {
    int pos = blockIdx.x;            // b*LL + l
    int b = pos / LL, l = pos % LL;
    int c = threadIdx.x;
    float v = x[((size_t)b*DIMC + c)*LL + l];
    float s = v, s2 = v*v;
    #pragma unroll
    for (int o = 32; o; o >>= 1) { s += __shfl_down(s, o); s2 += __shfl_down(s2, o); }
    __shared__ float ss[4], ss2[4];
    int wid = c >> 6;
    if ((c & 63) == 0) { ss[wid] = s; ss2[wid] = s2; }
    __syncthreads();
    float tot  = ss[0]+ss[1]+ss[2]+ss[3];
    float tot2 = ss2[0]+ss2[1]+ss2[2]+ss2[3];
    float mu = tot * (1.f/DIMC);
    float var = tot2 * (1.f/DIMC) - mu*mu;
    float r = rsqrtf(var + 1e-5f);
    xn[(size_t)pos*DIMC + c] = (v - mu)*r*w[c] + bgain[c];
}

// ---------------- Generic NT GEMM: C[M,N] = A[M,K(lda)] * Bw[N,K]^T ----------------
// EPI 0: plain store.  EPI 1: softplus(v + bias[col])
template<int EPI>
__global__ __launch_bounds__(256) void gemm_nt(const float* __restrict__ A, int lda,
    const float* __restrict__ Bw, const float* __restrict__ bias,
    float* __restrict__ C, int M, int N, int K) {
    __shared__ float As[16][68];
    __shared__ float Bs[16][68];
    int tid = threadIdx.x;
    int bm = blockIdx.y * 64;
    int bn = blockIdx.x * 64;
    int tm = (tid >> 4) * 4;
    int tn = (tid & 15) * 4;
    int ar = tid >> 2;           // 0..63
    int ak = (tid & 3) * 4;      // 0,4,8,12
    float acc[4][4] = {};
    for (int k0 = 0; k0 < K; k0 += 16) {
        float4 av = *(const float4*)(A + (size_t)(bm + ar) * lda + k0 + ak);
        As[ak+0][ar] = av.x; As[ak+1][ar] = av.y; As[ak+2][ar] = av.z; As[ak+3][ar] = av.w;
        float4 bv = make_float4(0.f,0.f,0.f,0.f);
        if (bn + ar < N) bv = *(const float4*)(Bw + (size_t)(bn + ar) * K + k0 + ak);
        Bs[ak+0][ar] = bv.x; Bs[ak+1][ar] = bv.y; Bs[ak+2][ar] = bv.z; Bs[ak+3][ar] = bv.w;
        __syncthreads();
        #pragma unroll
        for (int kk = 0; kk < 16; kk++) {
            float4 a4 = *(const float4*)&As[kk][tm];
            float4 b4 = *(const float4*)&Bs[kk][tn];
            float a[4] = {a4.x, a4.y, a4.z, a4.w};
            float b[4] = {b4.x, b4.y, b4.z, b4.w};
            #pragma unroll
            for (int i = 0; i < 4; i++)
                #pragma unroll
                for (int j = 0; j < 4; j++)
                    acc[i][j] = fmaf(a[i], b[j], acc[i][j]);
        }
        __syncthreads();
    }
    if (bn + tn < N) {
        #pragma unroll
        for (int i = 0; i < 4; i++) {
            int row = bm + tm + i;
            float4 v;
            float* pv = (float*)&v;
            #pragma unroll
            for (int j = 0; j < 4; j++) {
                float t = acc[i][j];
                if (EPI == 1) t = softplus_f(t + bias[bn + tn + j]);
                pv[j] = t;
            }
            *(float4*)(C + (size_t)row * N + bn + tn) = v;
        }
    }
}

// ---------------- causal depthwise conv (k=4) + SiLU: xz[:, :512] -> xu[M,512] ------
__global__ __launch_bounds__(256) void conv_kernel(const float* __restrict__ xz,
    const float* __restrict__ cw, const float* __restrict__ cb,
    float* __restrict__ xu) {
    int idx = blockIdx.x * 256 + threadIdx.x;   // over MM*DIN
    int d = idx & (DIN-1);
    int ml = idx >> 9;           // b*LL + l
    int l = ml % LL;
    float acc = cb[d];
    #pragma unroll
    for (int j = 0; j < 4; j++) {
        int ll = l - 3 + j;
        if (ll >= 0) acc = fmaf(cw[d*4 + j], xz[(size_t)(ml - l + ll)*1024 + d], acc);
    }
    xu[(size_t)ml*DIN + d] = silu_f(acc);
}

// ---------------- selective scan: 16 lanes per (b,d) channel ----------------
// delta[M,512], xu[M,512], x_dbl[M,48] (dt|B|C), A_log[512,16] -> y_ssm[M,512]
__global__ __launch_bounds__(64) void scan_kernel(const float* __restrict__ delta,
    const float* __restrict__ xu, const float* __restrict__ xdbl,
    const float* __restrict__ A_log, float* __restrict__ y_ssm) {
    int g = blockIdx.x * 4 + (threadIdx.x >> 4);   // (b,d) group, 0..1023
    int n = threadIdx.x & 15;
    int b = g >> 9;
    int d = g & (DIN-1);
    float A = -expf(A_log[d*DST + n]);
    float h = 0.f;
    int mbase = b * LL;
    for (int l = 0; l < LL; l++) {
        int m = mbase + l;
        float dlt = delta[(size_t)m*DIN + d];
        float xv  = xu[(size_t)m*DIN + d];
        float Bv  = xdbl[(size_t)m*48 + 16 + n];
        float Cv  = xdbl[(size_t)m*48 + 32 + n];
        float dA = expf(dlt * A);
        h = fmaf(dA, h, dlt * xv * Bv);
        float yv = h * Cv;
        yv += __shfl_xor(yv, 1);
        yv += __shfl_xor(yv, 2);
        yv += __shfl_xor(yv, 4);
        yv += __shfl_xor(yv, 8);
        if (n == 0) y_ssm[(size_t)m*DIN + d] = yv;
    }
}

// ---------------- gating: yg = (y_ssm + xu*D) * silu(z) ----------------
__global__ __launch_bounds__(256) void gate_kernel(const float* __restrict__ y_ssm,
    const float* __restrict__ xu, const float* __restrict__ Dp,
    const float* __restrict__ xz, float* __restrict__ yg) {
    int idx = blockIdx.x * 256 + threadIdx.x;   // over MM*DIN
    int d = idx & (DIN-1);
    int m = idx >> 9;
    float z = xz[(size_t)m*1024 + 512 + d];
    float y = fmaf(xu[idx], Dp[d], y_ssm[idx]);
    yg[idx] = y * silu_f(z);
}

// ---------------- final: out = x + gamma * transpose(yo) ----------------
__global__ __launch_bounds__(256) void final_kernel(const float* __restrict__ x,
    const float* __restrict__ yo, const float* __restrict__ gamma,
    float* __restrict__ out) {
    int idx = blockIdx.x * 256 + threadIdx.x;   // over B*C*L
    int l = idx % LL;
    int bc = idx / LL;
    int b = bc / DIMC, c = bc % DIMC;
    float g = gamma[0];
    out[idx] = fmaf(g, yo[(size_t)(b*LL + l)*DIMC + c], x[idx]);
}

extern "C" void kernel_launch(void* const* d_in, const int* in_sizes, int n_in,
                              void* d_out, int out_size, void* d_ws, size_t ws_size,
                              hipStream_t stream) {
    const float* x         = (const float*)d_in[0];
    const float* ln_w      = (const float*)d_in[1];
    const float* ln_b      = (const float*)d_in[2];
    const float* in_proj_w = (const float*)d_in[3];
    const float* conv_w    = (const float*)d_in[4];
    const float* conv_b    = (const float*)d_in[5];
    const float* x_proj_w  = (const float*)d_in[6];
    const float* dt_proj_w = (const float*)d_in[7];
    const float* dt_proj_b = (const float*)d_in[8];
    const float* A_log     = (const float*)d_in[9];
    const float* Dp        = (const float*)d_in[10];
    const float* out_proj_w= (const float*)d_in[11];
    const float* gamma     = (const float*)d_in[12];
    float* out = (float*)d_out;

    float* ws = (float*)d_ws;
    float* xn    = ws;                          // MM*256
    float* xz    = xn    + (size_t)MM*DIMC;     // MM*1024
    float* xu    = xz    + (size_t)MM*1024;     // MM*512
    float* x_dbl = xu    + (size_t)MM*DIN;      // MM*48
    float* delta = x_dbl + (size_t)MM*48;       // MM*512
    float* y_ssm = delta + (size_t)MM*DIN;      // MM*512
    float* yg    = y_ssm + (size_t)MM*DIN;      // MM*512
    float* yo    = yg    + (size_t)MM*DIN;      // MM*256

    // 1. LayerNorm
    ln_kernel<<<MM, 256, 0, stream>>>(x, ln_w, ln_b, xn);
    // 2. in_proj: xz = xn @ in_proj_w^T   [4608,1024]
    gemm_nt<0><<<dim3(1024/64, MM/64), 256, 0, stream>>>(xn, DIMC, in_proj_w, nullptr, xz, MM, 1024, DIMC);
    // 3. conv + silu -> xu
    conv_kernel<<<(MM*DIN)/256, 256, 0, stream>>>(xz, conv_w, conv_b, xu);
    // 4. x_proj: x_dbl = xu @ x_proj_w^T  [4608,48]
    gemm_nt<0><<<dim3(1, MM/64), 256, 0, stream>>>(xu, DIN, x_proj_w, nullptr, x_dbl, MM, 48, DIN);
    // 5. dt_proj + softplus -> delta  [4608,512]  (A = x_dbl first 16 cols, lda=48)
    gemm_nt<1><<<dim3(512/64, MM/64), 256, 0, stream>>>(x_dbl, 48, dt_proj_w, dt_proj_b, delta, MM, DIN, DTR);
    // 6. selective scan
    scan_kernel<<<256, 64, 0, stream>>>(delta, xu, x_dbl, A_log, y_ssm);
    // 7. gating
    gate_kernel<<<(MM*DIN)/256, 256, 0, stream>>>(y_ssm, xu, Dp, xz, yg);
    // 8. out_proj: yo = yg @ out_proj_w^T  [4608,256]
    gemm_nt<0><<<dim3(DIMC/64, MM/64), 256, 0, stream>>>(yg, DIN, out_proj_w, nullptr, yo, MM, DIMC, DIN);
    // 9. residual + gamma * transpose
    final_kernel<<<(BB*DIMC*LL)/256, 256, 0, stream>>>(x, yo, gamma, out);
}

// Round 2
// 311.313 us; speedup vs baseline: 4.0982x; 4.0982x over previous
//
#include <hip/hip_runtime.h>
#include <math.h>

#define DIMC 256
#define DST 16
#define DIN 512
#define DTR 16
#define BB 2
#define HH 48
#define WW 48
#define LL (HH*WW)      // 2304
#define MM (BB*LL)      // 4608
#define CH 96           // chunk length for the scan
#define NCH 24          // number of chunks (CH*NCH == LL)
#define NGRP (BB*DIN)   // 1024 (b,d) channels
#define NSEQ (NGRP*DST) // 16384 scalar recurrences

__device__ __forceinline__ float silu_f(float a){ return a / (1.f + expf(-a)); }
__device__ __forceinline__ float softplus_f(float a){ return a > 20.f ? a : log1pf(expf(a)); }

// ---------------- LayerNorm over channels: x[B,C,H,W] -> xn[B,L,C] ----------------
__global__ __launch_bounds__(256) void ln_kernel(const float* __restrict__ x,
    const float* __restrict__ w, const float* __restrict__ bgain,
    float* __restrict__ xn) {
    int pos = blockIdx.x;            // b*LL + l
    int b = pos / LL, l = pos % LL;
    int c = threadIdx.x;
    float v = x[((size_t)b*DIMC + c)*LL + l];
    float s = v, s2 = v*v;
    #pragma unroll
    for (int o = 32; o; o >>= 1) { s += __shfl_down(s, o); s2 += __shfl_down(s2, o); }
    __shared__ float ss[4], ss2[4];
    int wid = c >> 6;
    if ((c & 63) == 0) { ss[wid] = s; ss2[wid] = s2; }
    __syncthreads();
    float tot  = ss[0]+ss[1]+ss[2]+ss[3];
    float tot2 = ss2[0]+ss2[1]+ss2[2]+ss2[3];
    float mu = tot * (1.f/DIMC);
    float var = tot2 * (1.f/DIMC) - mu*mu;
    float r = rsqrtf(var + 1e-5f);
    xn[(size_t)pos*DIMC + c] = (v - mu)*r*w[c] + bgain[c];
}

// ---------------- Generic NT GEMM: C[M,N] = A[M,K(lda)] * Bw[N,K]^T ----------------
// EPI 0: plain store.  EPI 1: softplus(v + bias[col])
template<int EPI>
__global__ __launch_bounds__(256) void gemm_nt(const float* __restrict__ A, int lda,
    const float* __restrict__ Bw, const float* __restrict__ bias,
    float* __restrict__ C, int M, int N, int K) {
    __shared__ float As[16][68];
    __shared__ float Bs[16][68];
    int tid = threadIdx.x;
    int bm = blockIdx.y * 64;
    int bn = blockIdx.x * 64;
    int tm = (tid >> 4) * 4;
    int tn = (tid & 15) * 4;
    int ar = tid >> 2;           // 0..63
    int ak = (tid & 3) * 4;      // 0,4,8,12
    float acc[4][4] = {};
    for (int k0 = 0; k0 < K; k0 += 16) {
        float4 av = *(const float4*)(A + (size_t)(bm + ar) * lda + k0 + ak);
        As[ak+0][ar] = av.x; As[ak+1][ar] = av.y; As[ak+2][ar] = av.z; As[ak+3][ar] = av.w;
        float4 bv = make_float4(0.f,0.f,0.f,0.f);
        if (bn + ar < N) bv = *(const float4*)(Bw + (size_t)(bn + ar) * K + k0 + ak);
        Bs[ak+0][ar] = bv.x; Bs[ak+1][ar] = bv.y; Bs[ak+2][ar] = bv.z; Bs[ak+3][ar] = bv.w;
        __syncthreads();
        #pragma unroll
        for (int kk = 0; kk < 16; kk++) {
            float4 a4 = *(const float4*)&As[kk][tm];
            float4 b4 = *(const float4*)&Bs[kk][tn];
            float a[4] = {a4.x, a4.y, a4.z, a4.w};
            float b[4] = {b4.x, b4.y, b4.z, b4.w};
            #pragma unroll
            for (int i = 0; i < 4; i++)
                #pragma unroll
                for (int j = 0; j < 4; j++)
                    acc[i][j] = fmaf(a[i], b[j], acc[i][j]);
        }
        __syncthreads();
    }
    if (bn + tn < N) {
        #pragma unroll
        for (int i = 0; i < 4; i++) {
            int row = bm + tm + i;
            float4 v;
            float* pv = (float*)&v;
            #pragma unroll
            for (int j = 0; j < 4; j++) {
                float t = acc[i][j];
                if (EPI == 1) t = softplus_f(t + bias[bn + tn + j]);
                pv[j] = t;
            }
            *(float4*)(C + (size_t)row * N + bn + tn) = v;
        }
    }
}

// ---------------- causal depthwise conv (k=4) + SiLU: xz[:, :512] -> xu[M,512] ------
__global__ __launch_bounds__(256) void conv_kernel(const float* __restrict__ xz,
    const float* __restrict__ cw, const float* __restrict__ cb,
    float* __restrict__ xu) {
    int idx = blockIdx.x * 256 + threadIdx.x;   // over MM*DIN
    int d = idx & (DIN-1);
    int ml = idx >> 9;           // b*LL + l
    int l = ml % LL;
    float acc = cb[d];
    #pragma unroll
    for (int j = 0; j < 4; j++) {
        int ll = l - 3 + j;
        if (ll >= 0) acc = fmaf(cw[d*4 + j], xz[(size_t)(ml - l + ll)*1024 + d], acc);
    }
    xu[(size_t)ml*DIN + d] = silu_f(acc);
}

// ================= chunked selective scan (3 phases) =================
// Linear recurrence h = dA*h + dBx is associative:
//   (a1,b1) o (a2,b2) = (a1*a2, a2*b1 + b2)
// phase1: per (b,d,chunk) group of 16 lanes (n), scan chunk from h=0,
//         emit (prod dA, h_end) per n.
// phase2: per (b,d,n) scalar sequence, 24-step exclusive combine -> h_in/chunk.
// phase3: rescan each chunk from its true h_in, reduce over n, write y_ssm.

// group index t in [0, NGRP*NCH): c = t>>10 (chunk), g = t&1023 (b*512+d)
__global__ __launch_bounds__(256) void scan_phase1(const float* __restrict__ delta,
    const float* __restrict__ xu, const float* __restrict__ xdbl,
    const float* __restrict__ A_log, float* __restrict__ aprod,
    float* __restrict__ hend) {
    int t = blockIdx.x * 16 + (threadIdx.x >> 4);
    int n = threadIdx.x & 15;
    int c = t >> 10;
    int g = t & (NGRP-1);
    int b = g >> 9, d = g & (DIN-1);
    float A = -__expf(A_log[d*DST + n]);
    float a = 1.f, h = 0.f;
    int m0 = b*LL + c*CH;
    for (int l = 0; l < CH; l++) {
        int m = m0 + l;
        float dlt = delta[(size_t)m*DIN + d];
        float xv  = xu[(size_t)m*DIN + d];
        float Bv  = xdbl[(size_t)m*48 + 16 + n];
        float dA  = __expf(dlt * A);
        h = fmaf(dA, h, dlt * xv * Bv);
        a *= dA;
    }
    int ci = c*NSEQ + g*DST + n;   // chunk-outermost: coalesced everywhere
    aprod[ci] = a;
    hend[ci]  = h;
}

__global__ __launch_bounds__(256) void scan_phase2(const float* __restrict__ aprod,
    const float* __restrict__ hend, float* __restrict__ hin) {
    int u = blockIdx.x * 256 + threadIdx.x;   // 0..NSEQ-1
    float h = 0.f;
    #pragma unroll
    for (int c = 0; c < NCH; c++) {
        int ci = c*NSEQ + u;
        hin[ci] = h;
        h = fmaf(aprod[ci], h, hend[ci]);
    }
}

__global__ __launch_bounds__(256) void scan_phase3(const float* __restrict__ delta,
    const float* __restrict__ xu, const float* __restrict__ xdbl,
    const float* __restrict__ A_log, const float* __restrict__ hin,
    float* __restrict__ y_ssm) {
    int t = blockIdx.x * 16 + (threadIdx.x >> 4);
    int n = threadIdx.x & 15;
    int c = t >> 10;
    int g = t & (NGRP-1);
    int b = g >> 9, d = g & (DIN-1);
    float A = -__expf(A_log[d*DST + n]);
    float h = hin[c*NSEQ + g*DST + n];
    int m0 = b*LL + c*CH;
    for (int l = 0; l < CH; l++) {
        int m = m0 + l;
        float dlt = delta[(size_t)m*DIN + d];
        float xv  = xu[(size_t)m*DIN + d];
        float Bv  = xdbl[(size_t)m*48 + 16 + n];
        float Cv  = xdbl[(size_t)m*48 + 32 + n];
        float dA  = __expf(dlt * A);
        h = fmaf(dA, h, dlt * xv * Bv);
        float yv = h * Cv;
        yv += __shfl_xor(yv, 1);
        yv += __shfl_xor(yv, 2);
        yv += __shfl_xor(yv, 4);
        yv += __shfl_xor(yv, 8);
        if (n == 0) y_ssm[(size_t)m*DIN + d] = yv;
    }
}

// ---------------- gating: yg = (y_ssm + xu*D) * silu(z) ----------------
__global__ __launch_bounds__(256) void gate_kernel(const float* __restrict__ y_ssm,
    const float* __restrict__ xu, const float* __restrict__ Dp,
    const float* __restrict__ xz, float* __restrict__ yg) {
    int idx = blockIdx.x * 256 + threadIdx.x;   // over MM*DIN
    int d = idx & (DIN-1);
    int m = idx >> 9;
    float z = xz[(size_t)m*1024 + 512 + d];
    float y = fmaf(xu[idx], Dp[d], y_ssm[idx]);
    yg[idx] = y * silu_f(z);
}

// ---------------- final: out = x + gamma * transpose(yo) ----------------
__global__ __launch_bounds__(256) void final_kernel(const float* __restrict__ x,
    const float* __restrict__ yo, const float* __restrict__ gamma,
    float* __restrict__ out) {
    int idx = blockIdx.x * 256 + threadIdx.x;   // over B*C*L
    int l = idx % LL;
    int bc = idx / LL;
    int b = bc / DIMC, c = bc % DIMC;
    float g = gamma[0];
    out[idx] = fmaf(g, yo[(size_t)(b*LL + l)*DIMC + c], x[idx]);
}

extern "C" void kernel_launch(void* const* d_in, const int* in_sizes, int n_in,
                              void* d_out, int out_size, void* d_ws, size_t ws_size,
                              hipStream_t stream) {
    const float* x         = (const float*)d_in[0];
    const float* ln_w      = (const float*)d_in[1];
    const float* ln_b      = (const float*)d_in[2];
    const float* in_proj_w = (const float*)d_in[3];
    const float* conv_w    = (const float*)d_in[4];
    const float* conv_b    = (const float*)d_in[5];
    const float* x_proj_w  = (const float*)d_in[6];
    const float* dt_proj_w = (const float*)d_in[7];
    const float* dt_proj_b = (const float*)d_in[8];
    const float* A_log     = (const float*)d_in[9];
    const float* Dp        = (const float*)d_in[10];
    const float* out_proj_w= (const float*)d_in[11];
    const float* gamma     = (const float*)d_in[12];
    float* out = (float*)d_out;

    float* ws = (float*)d_ws;
    float* xn    = ws;                          // MM*256
    float* xz    = xn    + (size_t)MM*DIMC;     // MM*1024
    float* xu    = xz    + (size_t)MM*1024;     // MM*512
    float* x_dbl = xu    + (size_t)MM*DIN;      // MM*48
    float* delta = x_dbl + (size_t)MM*48;       // MM*512
    float* y_ssm = delta + (size_t)MM*DIN;      // MM*512
    float* yg    = y_ssm + (size_t)MM*DIN;      // MM*512
    float* yo    = yg    + (size_t)MM*DIN;      // MM*256
    // chunk-scan state arrays: 3 * NSEQ * NCH = 1,179,648 floats — exactly
    // the size of xn, which is dead after the in_proj GEMM. Alias it.
    float* aprod = xn;                          // NSEQ*NCH
    float* hend  = aprod + (size_t)NSEQ*NCH;    // NSEQ*NCH
    float* hin   = hend  + (size_t)NSEQ*NCH;    // NSEQ*NCH

    // 1. LayerNorm
    ln_kernel<<<MM, 256, 0, stream>>>(x, ln_w, ln_b, xn);
    // 2. in_proj: xz = xn @ in_proj_w^T   [4608,1024]
    gemm_nt<0><<<dim3(1024/64, MM/64), 256, 0, stream>>>(xn, DIMC, in_proj_w, nullptr, xz, MM, 1024, DIMC);
    // 3. conv + silu -> xu
    conv_kernel<<<(MM*DIN)/256, 256, 0, stream>>>(xz, conv_w, conv_b, xu);
    // 4. x_proj: x_dbl = xu @ x_proj_w^T  [4608,48]
    gemm_nt<0><<<dim3(1, MM/64), 256, 0, stream>>>(xu, DIN, x_proj_w, nullptr, x_dbl, MM, 48, DIN);
    // 5. dt_proj + softplus -> delta  [4608,512]
    gemm_nt<1><<<dim3(512/64, MM/64), 256, 0, stream>>>(x_dbl, 48, dt_proj_w, dt_proj_b, delta, MM, DIN, DTR);
    // 6. chunked selective scan (3 phases)
    scan_phase1<<<(NGRP*NCH)/16, 256, 0, stream>>>(delta, xu, x_dbl, A_log, aprod, hend);
    scan_phase2<<<NSEQ/256, 256, 0, stream>>>(aprod, hend, hin);
    scan_phase3<<<(NGRP*NCH)/16, 256, 0, stream>>>(delta, xu, x_dbl, A_log, hin, y_ssm);
    // 7. gating
    gate_kernel<<<(MM*DIN)/256, 256, 0, stream>>>(y_ssm, xu, Dp, xz, yg);
    // 8. out_proj: yo = yg @ out_proj_w^T  [4608,256]
    gemm_nt<0><<<dim3(DIMC/64, MM/64), 256, 0, stream>>>(yg, DIN, out_proj_w, nullptr, yo, MM, DIMC, DIN);
    // 9. residual + gamma * transpose
    final_kernel<<<(BB*DIMC*LL)/256, 256, 0, stream>>>(x, yo, gamma, out);
}

// Round 3
// 286.051 us; speedup vs baseline: 4.4601x; 1.0883x over previous
//
#include <hip/hip_runtime.h>
#include <math.h>

#define DIMC 256
#define DST 16
#define DIN 512
#define DTR 16
#define BB 2
#define HH 48
#define WW 48
#define LL (HH*WW)      // 2304
#define MM (BB*LL)      // 4608
#define CH 24           // chunk length for the scan
#define NC 96           // number of chunks (CH*NC == LL)
#define NGRP (BB*DIN)   // 1024 (b,d) channels
#define NSEQ (NGRP*DST) // 16384 scalar recurrences

__device__ __forceinline__ float silu_f(float a){ return a / (1.f + expf(-a)); }
__device__ __forceinline__ float softplus_f(float a){ return a > 20.f ? a : log1pf(__expf(a)); }

// ---------------- LayerNorm over channels: x[B,C,H,W] -> xn[B,L,C] ----------------
__global__ __launch_bounds__(256) void ln_kernel(const float* __restrict__ x,
    const float* __restrict__ w, const float* __restrict__ bgain,
    float* __restrict__ xn) {
    int pos = blockIdx.x;            // b*LL + l
    int b = pos / LL, l = pos % LL;
    int c = threadIdx.x;
    float v = x[((size_t)b*DIMC + c)*LL + l];
    float s = v, s2 = v*v;
    #pragma unroll
    for (int o = 32; o; o >>= 1) { s += __shfl_down(s, o); s2 += __shfl_down(s2, o); }
    __shared__ float ss[4], ss2[4];
    int wid = c >> 6;
    if ((c & 63) == 0) { ss[wid] = s; ss2[wid] = s2; }
    __syncthreads();
    float tot  = ss[0]+ss[1]+ss[2]+ss[3];
    float tot2 = ss2[0]+ss2[1]+ss2[2]+ss2[3];
    float mu = tot * (1.f/DIMC);
    float var = tot2 * (1.f/DIMC) - mu*mu;
    float r = rsqrtf(var + 1e-5f);
    xn[(size_t)pos*DIMC + c] = (v - mu)*r*w[c] + bgain[c];
}

// ---------------- Generic NT GEMM: C[M,N] = A[M,K(lda)] * Bw[N,K]^T ----------------
// EPI 0: plain store to C.
// EPI 2: transposed store fused with residual: Out[(b*DIMC+col)*LL + l] = X + gamma*acc
template<int EPI>
__global__ __launch_bounds__(256) void gemm_nt(const float* __restrict__ A, int lda,
    const float* __restrict__ Bw, float* __restrict__ C, int M, int N, int K,
    const float* __restrict__ Xres, const float* __restrict__ gammap,
    float* __restrict__ Out) {
    __shared__ float As[16][68];
    __shared__ float Bs[16][68];
    int tid = threadIdx.x;
    int bm = blockIdx.y * 64;
    int bn = blockIdx.x * 64;
    int tm = (tid >> 4) * 4;
    int tn = (tid & 15) * 4;
    int ar = tid >> 2;           // 0..63
    int ak = (tid & 3) * 4;      // 0,4,8,12
    float acc[4][4] = {};
    for (int k0 = 0; k0 < K; k0 += 16) {
        float4 av = *(const float4*)(A + (size_t)(bm + ar) * lda + k0 + ak);
        As[ak+0][ar] = av.x; As[ak+1][ar] = av.y; As[ak+2][ar] = av.z; As[ak+3][ar] = av.w;
        float4 bv = make_float4(0.f,0.f,0.f,0.f);
        if (bn + ar < N) bv = *(const float4*)(Bw + (size_t)(bn + ar) * K + k0 + ak);
        Bs[ak+0][ar] = bv.x; Bs[ak+1][ar] = bv.y; Bs[ak+2][ar] = bv.z; Bs[ak+3][ar] = bv.w;
        __syncthreads();
        #pragma unroll
        for (int kk = 0; kk < 16; kk++) {
            float4 a4 = *(const float4*)&As[kk][tm];
            float4 b4 = *(const float4*)&Bs[kk][tn];
            float a[4] = {a4.x, a4.y, a4.z, a4.w};
            float b[4] = {b4.x, b4.y, b4.z, b4.w};
            #pragma unroll
            for (int i = 0; i < 4; i++)
                #pragma unroll
                for (int j = 0; j < 4; j++)
                    acc[i][j] = fmaf(a[i], b[j], acc[i][j]);
        }
        __syncthreads();
    }
    if (EPI == 0) {
        if (bn + tn < N) {
            #pragma unroll
            for (int i = 0; i < 4; i++) {
                float4 v = make_float4(acc[i][0], acc[i][1], acc[i][2], acc[i][3]);
                *(float4*)(C + (size_t)(bm + tm + i) * N + bn + tn) = v;
            }
        }
    } else {
        // transposed store + residual. rows (64-aligned) never cross the b boundary
        float g = gammap[0];
        int b = bm / LL;
        int l0 = bm + tm - b*LL;
        #pragma unroll
        for (int j = 0; j < 4; j++) {
            int cc = bn + tn + j;
            size_t o = ((size_t)(b*DIMC + cc))*LL + l0;
            float4 xv = *(const float4*)(Xres + o);
            float4 v = make_float4(fmaf(g, acc[0][j], xv.x), fmaf(g, acc[1][j], xv.y),
                                   fmaf(g, acc[2][j], xv.z), fmaf(g, acc[3][j], xv.w));
            *(float4*)(Out + o) = v;
        }
    }
}

// ---------------- causal depthwise conv (k=4) + SiLU: xz[:, :512] -> xu[M,512] ------
__global__ __launch_bounds__(256) void conv_kernel(const float* __restrict__ xz,
    const float* __restrict__ cw, const float* __restrict__ cb,
    float* __restrict__ xu) {
    int idx = blockIdx.x * 256 + threadIdx.x;   // over MM*DIN
    int d = idx & (DIN-1);
    int ml = idx >> 9;           // b*LL + l
    int l = ml % LL;
    float acc = cb[d];
    #pragma unroll
    for (int j = 0; j < 4; j++) {
        int ll = l - 3 + j;
        if (ll >= 0) acc = fmaf(cw[d*4 + j], xz[(size_t)(ml - l + ll)*1024 + d], acc);
    }
    xu[(size_t)ml*DIN + d] = silu_f(acc);
}

// ================= chunked selective scan, thread-per-(chunk, b, d) =================
// Each thread owns all 16 n-states in registers. dt_proj+softplus fused (K=16 dot).
// phase1: scan chunk from h=0, emit per-n (prod dA, h_end).
// phase2: per (b,d,n): NC-step sequential combine -> true h_in per chunk.
// phase3: rescan from true h_in, reduce over n in-register, fuse gate, write yg.

#define LOAD16(arr, p) { float4 q0=(p)[0],q1=(p)[1],q2=(p)[2],q3=(p)[3]; \
    arr[0]=q0.x;arr[1]=q0.y;arr[2]=q0.z;arr[3]=q0.w; arr[4]=q1.x;arr[5]=q1.y;arr[6]=q1.z;arr[7]=q1.w; \
    arr[8]=q2.x;arr[9]=q2.y;arr[10]=q2.z;arr[11]=q2.w; arr[12]=q3.x;arr[13]=q3.y;arr[14]=q3.z;arr[15]=q3.w; }

__global__ __launch_bounds__(256) void scan_phase1(
    const float* __restrict__ xu, const float* __restrict__ xdbl,
    const float* __restrict__ dtw, const float* __restrict__ dtb,
    const float* __restrict__ A_log,
    float* __restrict__ aprod, float* __restrict__ hend) {
    int t = blockIdx.x * 256 + threadIdx.x;
    int g = t & (NGRP-1);
    int c = t >> 10;
    int b = g >> 9, d = g & (DIN-1);
    float dw[16], A[16], h[16], a[16];
    LOAD16(dw, (const float4*)(dtw + (size_t)d*16));
    #pragma unroll
    for (int n = 0; n < 16; n++) A[n] = -__expf(A_log[d*DST + n]);
    #pragma unroll
    for (int n = 0; n < 16; n++) { h[n] = 0.f; a[n] = 1.f; }
    float bias = dtb[d];
    int m0 = b*LL + c*CH;
    for (int l = 0; l < CH; l++) {
        int m = m0 + l;
        const float4* xr = (const float4*)(xdbl + (size_t)m*48);
        float4 t0 = xr[0], t1 = xr[1], t2 = xr[2], t3 = xr[3];
        float dlt = bias;
        dlt=fmaf(t0.x,dw[0],dlt); dlt=fmaf(t0.y,dw[1],dlt); dlt=fmaf(t0.z,dw[2],dlt); dlt=fmaf(t0.w,dw[3],dlt);
        dlt=fmaf(t1.x,dw[4],dlt); dlt=fmaf(t1.y,dw[5],dlt); dlt=fmaf(t1.z,dw[6],dlt); dlt=fmaf(t1.w,dw[7],dlt);
        dlt=fmaf(t2.x,dw[8],dlt); dlt=fmaf(t2.y,dw[9],dlt); dlt=fmaf(t2.z,dw[10],dlt); dlt=fmaf(t2.w,dw[11],dlt);
        dlt=fmaf(t3.x,dw[12],dlt); dlt=fmaf(t3.y,dw[13],dlt); dlt=fmaf(t3.z,dw[14],dlt); dlt=fmaf(t3.w,dw[15],dlt);
        dlt = softplus_f(dlt);
        float xv = xu[(size_t)m*DIN + d];
        float dbx = dlt * xv;
        float Bv[16];
        LOAD16(Bv, xr + 4);
        #pragma unroll
        for (int n = 0; n < 16; n++) {
            float dA = __expf(dlt * A[n]);
            h[n] = fmaf(dA, h[n], dbx * Bv[n]);
            a[n] *= dA;
        }
    }
    float4* ap = (float4*)(aprod + ((size_t)c*NGRP + g)*16);
    float4* hp = (float4*)(hend  + ((size_t)c*NGRP + g)*16);
    ap[0] = make_float4(a[0],a[1],a[2],a[3]);   ap[1] = make_float4(a[4],a[5],a[6],a[7]);
    ap[2] = make_float4(a[8],a[9],a[10],a[11]); ap[3] = make_float4(a[12],a[13],a[14],a[15]);
    hp[0] = make_float4(h[0],h[1],h[2],h[3]);   hp[1] = make_float4(h[4],h[5],h[6],h[7]);
    hp[2] = make_float4(h[8],h[9],h[10],h[11]); hp[3] = make_float4(h[12],h[13],h[14],h[15]);
}

__global__ __launch_bounds__(256) void scan_phase2(const float* __restrict__ aprod,
    const float* __restrict__ hend, float* __restrict__ hin) {
    int u = blockIdx.x * 256 + threadIdx.x;   // 0..NSEQ-1  (= g*16 + n)
    float h = 0.f;
    #pragma unroll 4
    for (int c = 0; c < NC; c++) {
        size_t ci = (size_t)c*NSEQ + u;
        hin[ci] = h;
        h = fmaf(aprod[ci], h, hend[ci]);
    }
}

__global__ __launch_bounds__(256) void scan_phase3(
    const float* __restrict__ xu, const float* __restrict__ xdbl,
    const float* __restrict__ dtw, const float* __restrict__ dtb,
    const float* __restrict__ A_log, const float* __restrict__ Dp,
    const float* __restrict__ xz, const float* __restrict__ hin,
    float* __restrict__ yg) {
    int t = blockIdx.x * 256 + threadIdx.x;
    int g = t & (NGRP-1);
    int c = t >> 10;
    int b = g >> 9, d = g & (DIN-1);
    float dw[16], A[16], h[16];
    LOAD16(dw, (const float4*)(dtw + (size_t)d*16));
    #pragma unroll
    for (int n = 0; n < 16; n++) A[n] = -__expf(A_log[d*DST + n]);
    LOAD16(h, (const float4*)(hin + ((size_t)c*NGRP + g)*16));
    float bias = dtb[d];
    float Dd = Dp[d];
    int m0 = b*LL + c*CH;
    for (int l = 0; l < CH; l++) {
        int m = m0 + l;
        const float4* xr = (const float4*)(xdbl + (size_t)m*48);
        float4 t0 = xr[0], t1 = xr[1], t2 = xr[2], t3 = xr[3];
        float dlt = bias;
        dlt=fmaf(t0.x,dw[0],dlt); dlt=fmaf(t0.y,dw[1],dlt); dlt=fmaf(t0.z,dw[2],dlt); dlt=fmaf(t0.w,dw[3],dlt);
        dlt=fmaf(t1.x,dw[4],dlt); dlt=fmaf(t1.y,dw[5],dlt); dlt=fmaf(t1.z,dw[6],dlt); dlt=fmaf(t1.w,dw[7],dlt);
        dlt=fmaf(t2.x,dw[8],dlt); dlt=fmaf(t2.y,dw[9],dlt); dlt=fmaf(t2.z,dw[10],dlt); dlt=fmaf(t2.w,dw[11],dlt);
        dlt=fmaf(t3.x,dw[12],dlt); dlt=fmaf(t3.y,dw[13],dlt); dlt=fmaf(t3.z,dw[14],dlt); dlt=fmaf(t3.w,dw[15],dlt);
        dlt = softplus_f(dlt);
        float xv = xu[(size_t)m*DIN + d];
        float dbx = dlt * xv;
        float Bv[16], Cv[16];
        LOAD16(Bv, xr + 4);
        LOAD16(Cv, xr + 8);
        float y = 0.f;
        #pragma unroll
        for (int n = 0; n < 16; n++) {
            float dA = __expf(dlt * A[n]);
            h[n] = fmaf(dA, h[n], dbx * Bv[n]);
            y = fmaf(h[n], Cv[n], y);
        }
        float z = xz[(size_t)m*1024 + 512 + d];
        float yv = fmaf(xv, Dd, y);
        yg[(size_t)m*DIN + d] = yv * (z / (1.f + __expf(-z)));
    }
}

extern "C" void kernel_launch(void* const* d_in, const int* in_sizes, int n_in,
                              void* d_out, int out_size, void* d_ws, size_t ws_size,
                              hipStream_t stream) {
    const float* x         = (const float*)d_in[0];
    const float* ln_w      = (const float*)d_in[1];
    const float* ln_b      = (const float*)d_in[2];
    const float* in_proj_w = (const float*)d_in[3];
    const float* conv_w    = (const float*)d_in[4];
    const float* conv_b    = (const float*)d_in[5];
    const float* x_proj_w  = (const float*)d_in[6];
    const float* dt_proj_w = (const float*)d_in[7];
    const float* dt_proj_b = (const float*)d_in[8];
    const float* A_log     = (const float*)d_in[9];
    const float* Dp        = (const float*)d_in[10];
    const float* out_proj_w= (const float*)d_in[11];
    const float* gamma     = (const float*)d_in[12];
    float* out = (float*)d_out;

    float* ws = (float*)d_ws;
    float* xn    = ws;                          // MM*256
    float* xz    = xn    + (size_t)MM*DIMC;     // MM*1024
    float* xu    = xz    + (size_t)MM*1024;     // MM*512
    float* x_dbl = xu    + (size_t)MM*DIN;      // MM*48
    float* aprod = x_dbl + (size_t)MM*48;       // NC*NSEQ
    float* hend  = aprod + (size_t)NC*NSEQ;     // NC*NSEQ
    float* hin   = hend  + (size_t)NC*NSEQ;     // NC*NSEQ
    float* yg    = hin   + (size_t)NC*NSEQ;     // MM*512

    // 1. LayerNorm
    ln_kernel<<<MM, 256, 0, stream>>>(x, ln_w, ln_b, xn);
    // 2. in_proj: xz = xn @ in_proj_w^T   [4608,1024]
    gemm_nt<0><<<dim3(1024/64, MM/64), 256, 0, stream>>>(xn, DIMC, in_proj_w, xz, MM, 1024, DIMC, nullptr, nullptr, nullptr);
    // 3. conv + silu -> xu
    conv_kernel<<<(MM*DIN)/256, 256, 0, stream>>>(xz, conv_w, conv_b, xu);
    // 4. x_proj: x_dbl = xu @ x_proj_w^T  [4608,48]
    gemm_nt<0><<<dim3(1, MM/64), 256, 0, stream>>>(xu, DIN, x_proj_w, x_dbl, MM, 48, DIN, nullptr, nullptr, nullptr);
    // 5-7. chunked selective scan (dt_proj+softplus fused; gate fused in phase3)
    scan_phase1<<<(NC*NGRP)/256, 256, 0, stream>>>(xu, x_dbl, dt_proj_w, dt_proj_b, A_log, aprod, hend);
    scan_phase2<<<NSEQ/256, 256, 0, stream>>>(aprod, hend, hin);
    scan_phase3<<<(NC*NGRP)/256, 256, 0, stream>>>(xu, x_dbl, dt_proj_w, dt_proj_b, A_log, Dp, xz, hin, yg);
    // 8. out_proj + residual + transpose, fused: out = x + gamma * (yg @ out_proj_w^T)^T'
    gemm_nt<2><<<dim3(DIMC/64, MM/64), 256, 0, stream>>>(yg, DIN, out_proj_w, nullptr, MM, DIMC, DIN, x, gamma, out);
}

// Round 5
// 212.392 us; speedup vs baseline: 6.0069x; 1.3468x over previous
//
#include <hip/hip_runtime.h>
#include <math.h>

#define DIMC 256
#define DST 16
#define DIN 512
#define BB 2
#define HH 48
#define WW 48
#define LL (HH*WW)      // 2304
#define MM (BB*LL)      // 4608
#define CH 24           // chunk length for the scan
#define NC 96           // number of chunks (CH*NC == LL)
#define NGRP (BB*DIN)   // 1024 (b,d) channels
#define NSEQ (NGRP*DST) // 16384 scalar recurrences

typedef unsigned short ushort_t;
typedef __attribute__((ext_vector_type(8))) short bf16x8;
typedef __attribute__((ext_vector_type(4))) float f32x4;

__device__ __forceinline__ float silu_f(float a){ return a / (1.f + expf(-a)); }
__device__ __forceinline__ float softplus_f(float a){ return a > 20.f ? a : log1pf(__expf(a)); }
__device__ __forceinline__ ushort_t f2bf(float f) {
    unsigned u = __float_as_uint(f);
    u += 0x7FFFu + ((u >> 16) & 1u);
    return (ushort_t)(u >> 16);
}
__device__ __forceinline__ float bf2f(ushort_t h) {
    return __uint_as_float(((unsigned)h) << 16);
}

// ---------------- LayerNorm over channels: x[B,C,H,W] -> xn[B,L,C] (bf16) ----------
__global__ __launch_bounds__(256) void ln_kernel(const float* __restrict__ x,
    const float* __restrict__ w, const float* __restrict__ bgain,
    ushort_t* __restrict__ xn) {
    int pos = blockIdx.x;            // b*LL + l
    int b = pos / LL, l = pos % LL;
    int c = threadIdx.x;
    float v = x[((size_t)b*DIMC + c)*LL + l];
    float s = v, s2 = v*v;
    #pragma unroll
    for (int o = 32; o; o >>= 1) { s += __shfl_down(s, o); s2 += __shfl_down(s2, o); }
    __shared__ float ss[4], ss2[4];
    int wid = c >> 6;
    if ((c & 63) == 0) { ss[wid] = s; ss2[wid] = s2; }
    __syncthreads();
    float tot  = ss[0]+ss[1]+ss[2]+ss[3];
    float tot2 = ss2[0]+ss2[1]+ss2[2]+ss2[3];
    float mu = tot * (1.f/DIMC);
    float var = tot2 * (1.f/DIMC) - mu*mu;
    float r = rsqrtf(var + 1e-5f);
    xn[(size_t)pos*DIMC + c] = f2bf((v - mu)*r*w[c] + bgain[c]);
}

// ---------------- weight fp32 -> bf16 conversion (all three, one launch) ----------
#define W0N (1024*256)
#define W1N (48*512)
#define W2N (256*512)
__global__ __launch_bounds__(256) void wconv_kernel(const float* __restrict__ w0,
    const float* __restrict__ w1, const float* __restrict__ w2,
    ushort_t* __restrict__ o0, ushort_t* __restrict__ o1, ushort_t* __restrict__ o2) {
    int i = blockIdx.x * 256 + threadIdx.x;     // [0, W0N+W1N+W2N)
    if (i < W0N) o0[i] = f2bf(w0[i]);
    else if (i < W0N + W1N) o1[i - W0N] = f2bf(w1[i - W0N]);
    else o2[i - W0N - W1N] = f2bf(w2[i - W0N - W1N]);
}

// ---------------- MFMA bf16 GEMM: C[M,N] = A[M,K] * W[N,K]^T --------------------
// 64x64 tile, BK=64, 256 threads = 4 waves (2x2), wave tile 32x32 = 2x2 frags of
// 16x16x32. A-frag: lane holds A[l&15][8*(l>>4)+j]; B-frag: W[l&15][8*(l>>4)+j];
// D: row=(l>>4)*4+i, col=l&15  (verified m89/m91 mapping).
// EPI 0: plain fp32 store (mask n<N). EPI 2: transposed store + residual.
template<int EPI>
__global__ __launch_bounds__(256) void mfma_gemm(const ushort_t* __restrict__ A,
    const ushort_t* __restrict__ W, float* __restrict__ C, int M, int N, int K,
    const float* __restrict__ Xres, const float* __restrict__ gammap,
    float* __restrict__ Out) {
    __shared__ ushort_t Asl[64][72];   // stride 144B: bank-uniform for b128 r/w
    __shared__ ushort_t Bsl[64][72];
    int tid = threadIdx.x;
    int bm = blockIdx.y * 64;
    int bn = blockIdx.x * 64;
    int w = tid >> 6, l = tid & 63;
    int wr = (w >> 1) * 32, wc = (w & 1) * 32;
    int fr = l & 15, fg = l >> 4;
    f32x4 acc[2][2] = {};
    for (int k0 = 0; k0 < K; k0 += 64) {
        #pragma unroll
        for (int s = 0; s < 2; s++) {
            int c = tid + s*256;           // 512 chunks of 8 bf16
            int r = c >> 3, c8 = (c & 7) * 8;
            *(uint4*)&Asl[r][c8] = *(const uint4*)(A + (size_t)(bm + r)*K + k0 + c8);
            uint4 wv = make_uint4(0u,0u,0u,0u);
            if (bn + r < N) wv = *(const uint4*)(W + (size_t)(bn + r)*K + k0 + c8);
            *(uint4*)&Bsl[r][c8] = wv;
        }
        __syncthreads();
        #pragma unroll
        for (int kk = 0; kk < 2; kk++) {
            int ko = kk*32 + fg*8;
            bf16x8 a0 = *(const bf16x8*)&Asl[wr + fr][ko];
            bf16x8 a1 = *(const bf16x8*)&Asl[wr + 16 + fr][ko];
            bf16x8 b0 = *(const bf16x8*)&Bsl[wc + fr][ko];
            bf16x8 b1 = *(const bf16x8*)&Bsl[wc + 16 + fr][ko];
            acc[0][0] = __builtin_amdgcn_mfma_f32_16x16x32_bf16(a0, b0, acc[0][0], 0,0,0);
            acc[0][1] = __builtin_amdgcn_mfma_f32_16x16x32_bf16(a0, b1, acc[0][1], 0,0,0);
            acc[1][0] = __builtin_amdgcn_mfma_f32_16x16x32_bf16(a1, b0, acc[1][0], 0,0,0);
            acc[1][1] = __builtin_amdgcn_mfma_f32_16x16x32_bf16(a1, b1, acc[1][1], 0,0,0);
        }
        __syncthreads();
    }
    if (EPI == 0) {
        #pragma unroll
        for (int mi = 0; mi < 2; mi++)
            #pragma unroll
            for (int nj = 0; nj < 2; nj++) {
                int n = bn + wc + nj*16 + fr;
                if (n < N) {
                    int mbase = bm + wr + mi*16 + fg*4;
                    #pragma unroll
                    for (int i = 0; i < 4; i++)
                        C[(size_t)(mbase + i)*N + n] = acc[mi][nj][i];
                }
            }
    } else {
        float g = gammap[0];
        int b = (bm >= LL) ? 1 : 0;     // 64-tiles never cross the batch boundary
        #pragma unroll
        for (int mi = 0; mi < 2; mi++)
            #pragma unroll
            for (int nj = 0; nj < 2; nj++) {
                int n = bn + wc + nj*16 + fr;         // channel
                int mbase = bm + wr + mi*16 + fg*4;   // seq pos
                #pragma unroll
                for (int i = 0; i < 4; i++) {
                    size_t o = ((size_t)(b*DIMC + n))*LL + (size_t)(mbase + i - b*LL);
                    Out[o] = fmaf(g, acc[mi][nj][i], Xres[o]);
                }
            }
    }
}

// ---------------- causal depthwise conv (k=4) + SiLU -> xu (bf16) ----------------
__global__ __launch_bounds__(256) void conv_kernel(const float* __restrict__ xz,
    const float* __restrict__ cw, const float* __restrict__ cb,
    ushort_t* __restrict__ xu) {
    int idx = blockIdx.x * 256 + threadIdx.x;   // over MM*DIN
    int d = idx & (DIN-1);
    int ml = idx >> 9;           // b*LL + l
    int l = ml % LL;
    float acc = cb[d];
    #pragma unroll
    for (int j = 0; j < 4; j++) {
        int ll = l - 3 + j;
        if (ll >= 0) acc = fmaf(cw[d*4 + j], xz[(size_t)(ml - l + ll)*1024 + d], acc);
    }
    xu[(size_t)ml*DIN + d] = f2bf(silu_f(acc));
}

// ================= chunked selective scan, thread-per-(chunk, b, d) =================
#define LOAD16(arr, p) { float4 q0=(p)[0],q1=(p)[1],q2=(p)[2],q3=(p)[3]; \
    arr[0]=q0.x;arr[1]=q0.y;arr[2]=q0.z;arr[3]=q0.w; arr[4]=q1.x;arr[5]=q1.y;arr[6]=q1.z;arr[7]=q1.w; \
    arr[8]=q2.x;arr[9]=q2.y;arr[10]=q2.z;arr[11]=q2.w; arr[12]=q3.x;arr[13]=q3.y;arr[14]=q3.z;arr[15]=q3.w; }

__global__ __launch_bounds__(256) void scan_phase1(
    const ushort_t* __restrict__ xu, const float* __restrict__ xdbl,
    const float* __restrict__ dtw, const float* __restrict__ dtb,
    const float* __restrict__ A_log,
    float* __restrict__ aprod, float* __restrict__ hend) {
    int t = blockIdx.x * 256 + threadIdx.x;
    int g = t & (NGRP-1);
    int c = t >> 10;
    int b = g >> 9, d = g & (DIN-1);
    float dw[16], A[16], h[16], a[16];
    LOAD16(dw, (const float4*)(dtw + (size_t)d*16));
    #pragma unroll
    for (int n = 0; n < 16; n++) A[n] = -__expf(A_log[d*DST + n]);
    #pragma unroll
    for (int n = 0; n < 16; n++) { h[n] = 0.f; a[n] = 1.f; }
    float bias = dtb[d];
    int m0 = b*LL + c*CH;
    for (int l = 0; l < CH; l++) {
        int m = m0 + l;
        const float4* xr = (const float4*)(xdbl + (size_t)m*48);
        float4 t0 = xr[0], t1 = xr[1], t2 = xr[2], t3 = xr[3];
        float dlt = bias;
        dlt=fmaf(t0.x,dw[0],dlt); dlt=fmaf(t0.y,dw[1],dlt); dlt=fmaf(t0.z,dw[2],dlt); dlt=fmaf(t0.w,dw[3],dlt);
        dlt=fmaf(t1.x,dw[4],dlt); dlt=fmaf(t1.y,dw[5],dlt); dlt=fmaf(t1.z,dw[6],dlt); dlt=fmaf(t1.w,dw[7],dlt);
        dlt=fmaf(t2.x,dw[8],dlt); dlt=fmaf(t2.y,dw[9],dlt); dlt=fmaf(t2.z,dw[10],dlt); dlt=fmaf(t2.w,dw[11],dlt);
        dlt=fmaf(t3.x,dw[12],dlt); dlt=fmaf(t3.y,dw[13],dlt); dlt=fmaf(t3.z,dw[14],dlt); dlt=fmaf(t3.w,dw[15],dlt);
        dlt = softplus_f(dlt);
        float xv = bf2f(xu[(size_t)m*DIN + d]);
        float dbx = dlt * xv;
        float Bv[16];
        LOAD16(Bv, xr + 4);
        #pragma unroll
        for (int n = 0; n < 16; n++) {
            float dA = __expf(dlt * A[n]);
            h[n] = fmaf(dA, h[n], dbx * Bv[n]);
            a[n] *= dA;
        }
    }
    float4* ap = (float4*)(aprod + ((size_t)c*NGRP + g)*16);
    float4* hp = (float4*)(hend  + ((size_t)c*NGRP + g)*16);
    ap[0] = make_float4(a[0],a[1],a[2],a[3]);   ap[1] = make_float4(a[4],a[5],a[6],a[7]);
    ap[2] = make_float4(a[8],a[9],a[10],a[11]); ap[3] = make_float4(a[12],a[13],a[14],a[15]);
    hp[0] = make_float4(h[0],h[1],h[2],h[3]);   hp[1] = make_float4(h[4],h[5],h[6],h[7]);
    hp[2] = make_float4(h[8],h[9],h[10],h[11]); hp[3] = make_float4(h[12],h[13],h[14],h[15]);
}

__global__ __launch_bounds__(256) void scan_phase2(const float* __restrict__ aprod,
    const float* __restrict__ hend, float* __restrict__ hin) {
    int u = blockIdx.x * 256 + threadIdx.x;   // 0..NSEQ-1  (= g*16 + n)
    float h = 0.f;
    #pragma unroll 4
    for (int c = 0; c < NC; c++) {
        size_t ci = (size_t)c*NSEQ + u;
        hin[ci] = h;
        h = fmaf(aprod[ci], h, hend[ci]);
    }
}

__global__ __launch_bounds__(256) void scan_phase3(
    const ushort_t* __restrict__ xu, const float* __restrict__ xdbl,
    const float* __restrict__ dtw, const float* __restrict__ dtb,
    const float* __restrict__ A_log, const float* __restrict__ Dp,
    const float* __restrict__ xz, const float* __restrict__ hin,
    ushort_t* __restrict__ yg) {
    int t = blockIdx.x * 256 + threadIdx.x;
    int g = t & (NGRP-1);
    int c = t >> 10;
    int b = g >> 9, d = g & (DIN-1);
    float dw[16], A[16], h[16];
    LOAD16(dw, (const float4*)(dtw + (size_t)d*16));
    #pragma unroll
    for (int n = 0; n < 16; n++) A[n] = -__expf(A_log[d*DST + n]);
    LOAD16(h, (const float4*)(hin + ((size_t)c*NGRP + g)*16));
    float bias = dtb[d];
    float Dd = Dp[d];
    int m0 = b*LL + c*CH;
    for (int l = 0; l < CH; l++) {
        int m = m0 + l;
        const float4* xr = (const float4*)(xdbl + (size_t)m*48);
        float4 t0 = xr[0], t1 = xr[1], t2 = xr[2], t3 = xr[3];
        float dlt = bias;
        dlt=fmaf(t0.x,dw[0],dlt); dlt=fmaf(t0.y,dw[1],dlt); dlt=fmaf(t0.z,dw[2],dlt); dlt=fmaf(t0.w,dw[3],dlt);
        dlt=fmaf(t1.x,dw[4],dlt); dlt=fmaf(t1.y,dw[5],dlt); dlt=fmaf(t1.z,dw[6],dlt); dlt=fmaf(t1.w,dw[7],dlt);
        dlt=fmaf(t2.x,dw[8],dlt); dlt=fmaf(t2.y,dw[9],dlt); dlt=fmaf(t2.z,dw[10],dlt); dlt=fmaf(t2.w,dw[11],dlt);
        dlt=fmaf(t3.x,dw[12],dlt); dlt=fmaf(t3.y,dw[13],dlt); dlt=fmaf(t3.z,dw[14],dlt); dlt=fmaf(t3.w,dw[15],dlt);
        dlt = softplus_f(dlt);
        float xv = bf2f(xu[(size_t)m*DIN + d]);
        float dbx = dlt * xv;
        float Bv[16], Cv[16];
        LOAD16(Bv, xr + 4);
        LOAD16(Cv, xr + 8);
        float y = 0.f;
        #pragma unroll
        for (int n = 0; n < 16; n++) {
            float dA = __expf(dlt * A[n]);
            h[n] = fmaf(dA, h[n], dbx * Bv[n]);
            y = fmaf(h[n], Cv[n], y);
        }
        float z = xz[(size_t)m*1024 + 512 + d];
        float yv = fmaf(xv, Dd, y);
        yg[(size_t)m*DIN + d] = f2bf(yv * (z / (1.f + __expf(-z))));
    }
}

extern "C" void kernel_launch(void* const* d_in, const int* in_sizes, int n_in,
                              void* d_out, int out_size, void* d_ws, size_t ws_size,
                              hipStream_t stream) {
    const float* x         = (const float*)d_in[0];
    const float* ln_w      = (const float*)d_in[1];
    const float* ln_b      = (const float*)d_in[2];
    const float* in_proj_w = (const float*)d_in[3];
    const float* conv_w    = (const float*)d_in[4];
    const float* conv_b    = (const float*)d_in[5];
    const float* x_proj_w  = (const float*)d_in[6];
    const float* dt_proj_w = (const float*)d_in[7];
    const float* dt_proj_b = (const float*)d_in[8];
    const float* A_log     = (const float*)d_in[9];
    const float* Dp        = (const float*)d_in[10];
    const float* out_proj_w= (const float*)d_in[11];
    const float* gamma     = (const float*)d_in[12];
    float* out = (float*)d_out;

    float* ws = (float*)d_ws;
    float* xz    = ws;                          // MM*1024 fp32
    float* x_dbl = xz    + (size_t)MM*1024;     // MM*48
    float* aprod = x_dbl + (size_t)MM*48;       // NC*NSEQ
    float* hend  = aprod + (size_t)NC*NSEQ;     // NC*NSEQ
    float* hin   = hend  + (size_t)NC*NSEQ;     // NC*NSEQ
    ushort_t* xn  = (ushort_t*)(hin + (size_t)NC*NSEQ);  // MM*256 bf16
    ushort_t* xu  = xn  + (size_t)MM*DIMC;      // MM*512 bf16
    ushort_t* yg  = xu  + (size_t)MM*DIN;       // MM*512 bf16
    ushort_t* win = yg  + (size_t)MM*DIN;       // 1024*256 bf16
    ushort_t* wxp = win + (size_t)W0N;          // 48*512 bf16
    ushort_t* wout= wxp + (size_t)W1N;          // 256*512 bf16

    // 1. LayerNorm -> xn (bf16)
    ln_kernel<<<MM, 256, 0, stream>>>(x, ln_w, ln_b, xn);
    // 1b. weights -> bf16
    wconv_kernel<<<(W0N+W1N+W2N)/256, 256, 0, stream>>>(in_proj_w, x_proj_w, out_proj_w, win, wxp, wout);
    // 2. in_proj: xz = xn @ win^T   [4608,1024]
    mfma_gemm<0><<<dim3(1024/64, MM/64), 256, 0, stream>>>(xn, win, xz, MM, 1024, DIMC, nullptr, nullptr, nullptr);
    // 3. conv + silu -> xu (bf16)
    conv_kernel<<<(MM*DIN)/256, 256, 0, stream>>>(xz, conv_w, conv_b, xu);
    // 4. x_proj: x_dbl = xu @ wxp^T  [4608,48]
    mfma_gemm<0><<<dim3(1, MM/64), 256, 0, stream>>>(xu, wxp, x_dbl, MM, 48, DIN, nullptr, nullptr, nullptr);
    // 5-7. chunked selective scan (dt_proj+softplus fused; gate fused in phase3)
    scan_phase1<<<(NC*NGRP)/256, 256, 0, stream>>>(xu, x_dbl, dt_proj_w, dt_proj_b, A_log, aprod, hend);
    scan_phase2<<<NSEQ/256, 256, 0, stream>>>(aprod, hend, hin);
    scan_phase3<<<(NC*NGRP)/256, 256, 0, stream>>>(xu, x_dbl, dt_proj_w, dt_proj_b, A_log, Dp, xz, hin, yg);
    // 8. out_proj + residual + transpose fused
    mfma_gemm<2><<<dim3(DIMC/64, MM/64), 256, 0, stream>>>(yg, wout, nullptr, MM, DIMC, DIN, x, gamma, out);
}

// Round 6
// 202.496 us; speedup vs baseline: 6.3004x; 1.0489x over previous
//
#include <hip/hip_runtime.h>
#include <math.h>

#define DIMC 256
#define DST 16
#define DIN 512
#define BB 2
#define HH 48
#define WW 48
#define LL (HH*WW)      // 2304
#define MM (BB*LL)      // 4608
#define CH 12           // chunk length for the scan
#define NC 192          // number of chunks (CH*NC == LL)
#define NGRP (BB*DIN)   // 1024 (b,d) channels
#define NSEQ (NGRP*DST) // 16384 scalar recurrences
#define LTILE 16        // LN positions per block

typedef unsigned short ushort_t;
typedef __attribute__((ext_vector_type(8))) short bf16x8;
typedef __attribute__((ext_vector_type(4))) float f32x4;

__device__ __forceinline__ float silu_f(float a){ return a / (1.f + expf(-a)); }
__device__ __forceinline__ float softplus_f(float a){ return a > 20.f ? a : log1pf(__expf(a)); }
__device__ __forceinline__ ushort_t f2bf(float f) {
    unsigned u = __float_as_uint(f);
    u += 0x7FFFu + ((u >> 16) & 1u);
    return (ushort_t)(u >> 16);
}
__device__ __forceinline__ float bf2f(ushort_t h) {
    return __uint_as_float(((unsigned)h) << 16);
}

// ---------------- LayerNorm, tiled: x[B,C,H,W] -> xn[B,L,C] (bf16) ----------------
// Block = 16 positions x 256 channels. Coalesced segment reads, LDS transpose out.
__global__ __launch_bounds__(256) void ln_kernel(const float* __restrict__ x,
    const float* __restrict__ w, const float* __restrict__ bgain,
    ushort_t* __restrict__ xn) {
    __shared__ float T2[LTILE][DIMC + 4];   // stride 260 words: 16B-aligned rows
    __shared__ float PS[16][17], PS2[16][17];
    __shared__ float MUB[LTILE], RB[LTILE];
    int blk = blockIdx.x;            // 0 .. BB*(LL/LTILE)-1
    int b = blk / (LL/LTILE);
    int l0 = (blk % (LL/LTILE)) * LTILE;
    int t = threadIdx.x;
    int p = t & 15, g = t >> 4;      // position, channel-group
    float v[16];
    float s = 0.f, s2 = 0.f;
    #pragma unroll
    for (int cc = 0; cc < 16; cc++) {
        int c = g*16 + cc;
        float vv = x[((size_t)(b*DIMC + c))*LL + l0 + p];
        v[cc] = vv;
        s += vv; s2 += vv*vv;
    }
    PS[g][p] = s; PS2[g][p] = s2;
    __syncthreads();
    if (t < 16) {
        float tot = 0.f, tot2 = 0.f;
        #pragma unroll
        for (int gg = 0; gg < 16; gg++) { tot += PS[gg][t]; tot2 += PS2[gg][t]; }
        float mu = tot * (1.f/DIMC);
        float var = tot2 * (1.f/DIMC) - mu*mu;
        MUB[t] = mu;
        RB[t] = rsqrtf(var + 1e-5f);
    }
    __syncthreads();
    float mu = MUB[p], r = RB[p];
    #pragma unroll
    for (int cc = 0; cc < 16; cc++) {
        int c = g*16 + cc;
        T2[p][c] = (v[cc] - mu) * r * w[c] + bgain[c];
    }
    __syncthreads();
    int c4 = (t & 63) * 4;
    int prow = t >> 6;               // 0..3
    #pragma unroll
    for (int pp = 0; pp < 4; pp++) {
        int pos = pp*4 + prow;
        float4 q = *(const float4*)&T2[pos][c4];
        ushort4 o;
        o.x = f2bf(q.x); o.y = f2bf(q.y); o.z = f2bf(q.z); o.w = f2bf(q.w);
        *(ushort4*)&xn[((size_t)(b*LL + l0 + pos))*DIMC + c4] = o;
    }
}

// --------- setup: weights fp32->bf16, plus A2 = -exp(A_log) precompute -----------
#define W0N (1024*256)
#define W1N (48*512)
#define W2N (256*512)
__global__ __launch_bounds__(256) void wsetup_kernel(const float* __restrict__ w0,
    const float* __restrict__ w1, const float* __restrict__ w2,
    const float* __restrict__ A_log,
    ushort_t* __restrict__ o0, ushort_t* __restrict__ o1, ushort_t* __restrict__ o2,
    float* __restrict__ A2) {
    int i = blockIdx.x * 256 + threadIdx.x;
    if (i < W0N) o0[i] = f2bf(w0[i]);
    else if (i < W0N + W1N) o1[i - W0N] = f2bf(w1[i - W0N]);
    else if (i < W0N + W1N + W2N) o2[i - W0N - W1N] = f2bf(w2[i - W0N - W1N]);
    if (i < DIN*DST) A2[i] = -__expf(A_log[i]);
}

// ------- 128x128 MFMA GEMM for in_proj, split epilogue: xs bf16 | z fp32 ---------
// 4 waves (2x2), wave tile 64x64 = 4x4 frags of 16x16x32, BK=64.
__global__ __launch_bounds__(256) void mfma_gemm128_split(const ushort_t* __restrict__ A,
    const ushort_t* __restrict__ W, ushort_t* __restrict__ Xs, float* __restrict__ Zb,
    int K) {   // M=MM, N=1024
    __shared__ ushort_t Asl[128][72];
    __shared__ ushort_t Bsl[128][72];
    int tid = threadIdx.x;
    int bm = blockIdx.y * 128;
    int bn = blockIdx.x * 128;
    int w = tid >> 6, l = tid & 63;
    int wr = (w >> 1) * 64, wc = (w & 1) * 64;
    int fr = l & 15, fg = l >> 4;
    f32x4 acc[4][4] = {};
    for (int k0 = 0; k0 < K; k0 += 64) {
        #pragma unroll
        for (int s = 0; s < 4; s++) {
            int c = tid + s*256;           // 1024 chunks of 8 bf16
            int r = c >> 3, c8 = (c & 7) * 8;
            *(uint4*)&Asl[r][c8] = *(const uint4*)(A + (size_t)(bm + r)*K + k0 + c8);
            *(uint4*)&Bsl[r][c8] = *(const uint4*)(W + (size_t)(bn + r)*K + k0 + c8);
        }
        __syncthreads();
        #pragma unroll
        for (int kk = 0; kk < 2; kk++) {
            int ko = kk*32 + fg*8;
            bf16x8 af[4], bf[4];
            #pragma unroll
            for (int i = 0; i < 4; i++) af[i] = *(const bf16x8*)&Asl[wr + i*16 + fr][ko];
            #pragma unroll
            for (int j = 0; j < 4; j++) bf[j] = *(const bf16x8*)&Bsl[wc + j*16 + fr][ko];
            #pragma unroll
            for (int i = 0; i < 4; i++)
                #pragma unroll
                for (int j = 0; j < 4; j++)
                    acc[i][j] = __builtin_amdgcn_mfma_f32_16x16x32_bf16(af[i], bf[j], acc[i][j], 0,0,0);
        }
        __syncthreads();
    }
    #pragma unroll
    for (int i = 0; i < 4; i++)
        #pragma unroll
        for (int j = 0; j < 4; j++) {
            int n = bn + wc + j*16 + fr;
            int mbase = bm + wr + i*16 + fg*4;
            if (n < DIN) {
                #pragma unroll
                for (int ii = 0; ii < 4; ii++)
                    Xs[(size_t)(mbase+ii)*DIN + n] = f2bf(acc[i][j][ii]);
            } else {
                #pragma unroll
                for (int ii = 0; ii < 4; ii++)
                    Zb[(size_t)(mbase+ii)*DIN + (n - DIN)] = acc[i][j][ii];
            }
        }
}

// ---------------- 64x64 MFMA GEMM (x_proj EPI0 / out_proj EPI2) ------------------
template<int EPI>
__global__ __launch_bounds__(256) void mfma_gemm(const ushort_t* __restrict__ A,
    const ushort_t* __restrict__ W, float* __restrict__ C, int M, int N, int K,
    const float* __restrict__ Xres, const float* __restrict__ gammap,
    float* __restrict__ Out) {
    __shared__ ushort_t Asl[64][72];
    __shared__ ushort_t Bsl[64][72];
    int tid = threadIdx.x;
    int bm = blockIdx.y * 64;
    int bn = blockIdx.x * 64;
    int w = tid >> 6, l = tid & 63;
    int wr = (w >> 1) * 32, wc = (w & 1) * 32;
    int fr = l & 15, fg = l >> 4;
    f32x4 acc[2][2] = {};
    for (int k0 = 0; k0 < K; k0 += 64) {
        #pragma unroll
        for (int s = 0; s < 2; s++) {
            int c = tid + s*256;
            int r = c >> 3, c8 = (c & 7) * 8;
            *(uint4*)&Asl[r][c8] = *(const uint4*)(A + (size_t)(bm + r)*K + k0 + c8);
            uint4 wv = make_uint4(0u,0u,0u,0u);
            if (bn + r < N) wv = *(const uint4*)(W + (size_t)(bn + r)*K + k0 + c8);
            *(uint4*)&Bsl[r][c8] = wv;
        }
        __syncthreads();
        #pragma unroll
        for (int kk = 0; kk < 2; kk++) {
            int ko = kk*32 + fg*8;
            bf16x8 a0 = *(const bf16x8*)&Asl[wr + fr][ko];
            bf16x8 a1 = *(const bf16x8*)&Asl[wr + 16 + fr][ko];
            bf16x8 b0 = *(const bf16x8*)&Bsl[wc + fr][ko];
            bf16x8 b1 = *(const bf16x8*)&Bsl[wc + 16 + fr][ko];
            acc[0][0] = __builtin_amdgcn_mfma_f32_16x16x32_bf16(a0, b0, acc[0][0], 0,0,0);
            acc[0][1] = __builtin_amdgcn_mfma_f32_16x16x32_bf16(a0, b1, acc[0][1], 0,0,0);
            acc[1][0] = __builtin_amdgcn_mfma_f32_16x16x32_bf16(a1, b0, acc[1][0], 0,0,0);
            acc[1][1] = __builtin_amdgcn_mfma_f32_16x16x32_bf16(a1, b1, acc[1][1], 0,0,0);
        }
        __syncthreads();
    }
    if (EPI == 0) {
        #pragma unroll
        for (int mi = 0; mi < 2; mi++)
            #pragma unroll
            for (int nj = 0; nj < 2; nj++) {
                int n = bn + wc + nj*16 + fr;
                if (n < N) {
                    int mbase = bm + wr + mi*16 + fg*4;
                    #pragma unroll
                    for (int i = 0; i < 4; i++)
                        C[(size_t)(mbase + i)*N + n] = acc[mi][nj][i];
                }
            }
    } else {
        float g = gammap[0];
        int b = (bm >= LL) ? 1 : 0;
        #pragma unroll
        for (int mi = 0; mi < 2; mi++)
            #pragma unroll
            for (int nj = 0; nj < 2; nj++) {
                int n = bn + wc + nj*16 + fr;
                int mbase = bm + wr + mi*16 + fg*4;
                #pragma unroll
                for (int i = 0; i < 4; i++) {
                    size_t o = ((size_t)(b*DIMC + n))*LL + (size_t)(mbase + i - b*LL);
                    Out[o] = fmaf(g, acc[mi][nj][i], Xres[o]);
                }
            }
    }
}

// ---------------- causal depthwise conv (k=4) + SiLU: xs(bf16) -> xu (bf16) -------
__global__ __launch_bounds__(256) void conv_kernel(const ushort_t* __restrict__ xs,
    const float* __restrict__ cw, const float* __restrict__ cb,
    ushort_t* __restrict__ xu) {
    int idx = blockIdx.x * 256 + threadIdx.x;   // over MM*DIN
    int d = idx & (DIN-1);
    int ml = idx >> 9;
    int l = ml % LL;
    float acc = cb[d];
    #pragma unroll
    for (int j = 0; j < 4; j++) {
        int ll = l - 3 + j;
        if (ll >= 0) acc = fmaf(cw[d*4 + j], bf2f(xs[(size_t)(ml - l + ll)*DIN + d]), acc);
    }
    xu[(size_t)ml*DIN + d] = f2bf(silu_f(acc));
}

// ================= chunked selective scan, thread-per-(chunk, b, d) ================
// All 256 threads in a block share (b, chunk) -> same m-sequence: x_dbl rows staged
// in LDS once per block; in-loop reads are same-address broadcasts.
#define LOAD16(arr, p) { float4 q0=(p)[0],q1=(p)[1],q2=(p)[2],q3=(p)[3]; \
    arr[0]=q0.x;arr[1]=q0.y;arr[2]=q0.z;arr[3]=q0.w; arr[4]=q1.x;arr[5]=q1.y;arr[6]=q1.z;arr[7]=q1.w; \
    arr[8]=q2.x;arr[9]=q2.y;arr[10]=q2.z;arr[11]=q2.w; arr[12]=q3.x;arr[13]=q3.y;arr[14]=q3.z;arr[15]=q3.w; }

#define DT_DOT(dlt, xr) { float4 t0 = (xr)[0], t1 = (xr)[1], t2 = (xr)[2], t3 = (xr)[3]; \
    dlt=fmaf(t0.x,dw[0],dlt); dlt=fmaf(t0.y,dw[1],dlt); dlt=fmaf(t0.z,dw[2],dlt); dlt=fmaf(t0.w,dw[3],dlt); \
    dlt=fmaf(t1.x,dw[4],dlt); dlt=fmaf(t1.y,dw[5],dlt); dlt=fmaf(t1.z,dw[6],dlt); dlt=fmaf(t1.w,dw[7],dlt); \
    dlt=fmaf(t2.x,dw[8],dlt); dlt=fmaf(t2.y,dw[9],dlt); dlt=fmaf(t2.z,dw[10],dlt); dlt=fmaf(t2.w,dw[11],dlt); \
    dlt=fmaf(t3.x,dw[12],dlt); dlt=fmaf(t3.y,dw[13],dlt); dlt=fmaf(t3.z,dw[14],dlt); dlt=fmaf(t3.w,dw[15],dlt); }

__global__ __launch_bounds__(256) void scan_phase1(
    const ushort_t* __restrict__ xu, const float* __restrict__ xdbl,
    const float* __restrict__ dtw, const float* __restrict__ dtb,
    const float* __restrict__ A2,
    float* __restrict__ aprod, float* __restrict__ hend) {
    __shared__ float xs_s[CH*48];
    int t = blockIdx.x * 256 + threadIdx.x;
    int g = t & (NGRP-1);
    int c = t >> 10;
    int b = g >> 9, d = g & (DIN-1);
    int m0 = b*LL + c*CH;
    for (int i = threadIdx.x; i < CH*48; i += 256) xs_s[i] = xdbl[(size_t)m0*48 + i];
    float dw[16], A[16], h[16], a[16];
    LOAD16(dw, (const float4*)(dtw + (size_t)d*16));
    LOAD16(A,  (const float4*)(A2  + (size_t)d*16));
    #pragma unroll
    for (int n = 0; n < 16; n++) { h[n] = 0.f; a[n] = 1.f; }
    float bias = dtb[d];
    __syncthreads();
    for (int l = 0; l < CH; l++) {
        const float4* xr = (const float4*)&xs_s[l*48];
        float dlt = bias;
        DT_DOT(dlt, xr);
        dlt = softplus_f(dlt);
        float xv = bf2f(xu[(size_t)(m0 + l)*DIN + d]);
        float dbx = dlt * xv;
        float Bv[16];
        LOAD16(Bv, xr + 4);
        #pragma unroll
        for (int n = 0; n < 16; n++) {
            float dA = __expf(dlt * A[n]);
            h[n] = fmaf(dA, h[n], dbx * Bv[n]);
            a[n] *= dA;
        }
    }
    float4* ap = (float4*)(aprod + ((size_t)c*NGRP + g)*16);
    float4* hp = (float4*)(hend  + ((size_t)c*NGRP + g)*16);
    ap[0] = make_float4(a[0],a[1],a[2],a[3]);   ap[1] = make_float4(a[4],a[5],a[6],a[7]);
    ap[2] = make_float4(a[8],a[9],a[10],a[11]); ap[3] = make_float4(a[12],a[13],a[14],a[15]);
    hp[0] = make_float4(h[0],h[1],h[2],h[3]);   hp[1] = make_float4(h[4],h[5],h[6],h[7]);
    hp[2] = make_float4(h[8],h[9],h[10],h[11]); hp[3] = make_float4(h[12],h[13],h[14],h[15]);
}

__global__ __launch_bounds__(256) void scan_phase2(const float* __restrict__ aprod,
    const float* __restrict__ hend, float* __restrict__ hin) {
    int u = blockIdx.x * 256 + threadIdx.x;   // 0..NSEQ-1
    float h = 0.f;
    #pragma unroll 4
    for (int c = 0; c < NC; c++) {
        size_t ci = (size_t)c*NSEQ + u;
        hin[ci] = h;
        h = fmaf(aprod[ci], h, hend[ci]);
    }
}

__global__ __launch_bounds__(256) void scan_phase3(
    const ushort_t* __restrict__ xu, const float* __restrict__ xdbl,
    const float* __restrict__ dtw, const float* __restrict__ dtb,
    const float* __restrict__ A2, const float* __restrict__ Dp,
    const float* __restrict__ zbuf, const float* __restrict__ hin,
    ushort_t* __restrict__ yg) {
    __shared__ float xs_s[CH*48];
    int t = blockIdx.x * 256 + threadIdx.x;
    int g = t & (NGRP-1);
    int c = t >> 10;
    int b = g >> 9, d = g & (DIN-1);
    int m0 = b*LL + c*CH;
    for (int i = threadIdx.x; i < CH*48; i += 256) xs_s[i] = xdbl[(size_t)m0*48 + i];
    float dw[16], A[16], h[16];
    LOAD16(dw, (const float4*)(dtw + (size_t)d*16));
    LOAD16(A,  (const float4*)(A2  + (size_t)d*16));
    LOAD16(h,  (const float4*)(hin + ((size_t)c*NGRP + g)*16));
    float bias = dtb[d];
    float Dd = Dp[d];
    __syncthreads();
    for (int l = 0; l < CH; l++) {
        int m = m0 + l;
        const float4* xr = (const float4*)&xs_s[l*48];
        float dlt = bias;
        DT_DOT(dlt, xr);
        dlt = softplus_f(dlt);
        float xv = bf2f(xu[(size_t)m*DIN + d]);
        float dbx = dlt * xv;
        float Bv[16], Cv[16];
        LOAD16(Bv, xr + 4);
        LOAD16(Cv, xr + 8);
        float y = 0.f;
        #pragma unroll
        for (int n = 0; n < 16; n++) {
            float dA = __expf(dlt * A[n]);
            h[n] = fmaf(dA, h[n], dbx * Bv[n]);
            y = fmaf(h[n], Cv[n], y);
        }
        float z = zbuf[(size_t)m*DIN + d];
        float yv = fmaf(xv, Dd, y);
        yg[(size_t)m*DIN + d] = f2bf(yv * (z / (1.f + __expf(-z))));
    }
}

extern "C" void kernel_launch(void* const* d_in, const int* in_sizes, int n_in,
                              void* d_out, int out_size, void* d_ws, size_t ws_size,
                              hipStream_t stream) {
    const float* x         = (const float*)d_in[0];
    const float* ln_w      = (const float*)d_in[1];
    const float* ln_b      = (const float*)d_in[2];
    const float* in_proj_w = (const float*)d_in[3];
    const float* conv_w    = (const float*)d_in[4];
    const float* conv_b    = (const float*)d_in[5];
    const float* x_proj_w  = (const float*)d_in[6];
    const float* dt_proj_w = (const float*)d_in[7];
    const float* dt_proj_b = (const float*)d_in[8];
    const float* A_log     = (const float*)d_in[9];
    const float* Dp        = (const float*)d_in[10];
    const float* out_proj_w= (const float*)d_in[11];
    const float* gamma     = (const float*)d_in[12];
    float* out = (float*)d_out;

    float* ws = (float*)d_ws;
    float* zbuf  = ws;                          // MM*512 fp32 (z half of in_proj)
    float* x_dbl = zbuf  + (size_t)MM*DIN;      // MM*48
    float* aprod = x_dbl + (size_t)MM*48;       // NC*NSEQ
    float* hend  = aprod + (size_t)NC*NSEQ;     // NC*NSEQ
    float* hin   = hend  + (size_t)NC*NSEQ;     // NC*NSEQ
    float* A2    = hin   + (size_t)NC*NSEQ;     // DIN*DST
    ushort_t* xn  = (ushort_t*)(A2 + DIN*DST);  // MM*256 bf16
    ushort_t* xs  = xn  + (size_t)MM*DIMC;      // MM*512 bf16 (x half of in_proj)
    ushort_t* xu  = xs  + (size_t)MM*DIN;       // MM*512 bf16
    ushort_t* yg  = xu  + (size_t)MM*DIN;       // MM*512 bf16
    ushort_t* win = yg  + (size_t)MM*DIN;       // 1024*256 bf16
    ushort_t* wxp = win + (size_t)W0N;          // 48*512 bf16
    ushort_t* wout= wxp + (size_t)W1N;          // 256*512 bf16

    // 1. LayerNorm -> xn (bf16), tiled/coalesced
    ln_kernel<<<BB*(LL/LTILE), 256, 0, stream>>>(x, ln_w, ln_b, xn);
    // 1b. weights -> bf16; A2 = -exp(A_log)
    wsetup_kernel<<<(W0N+W1N+W2N+255)/256, 256, 0, stream>>>(in_proj_w, x_proj_w, out_proj_w, A_log, win, wxp, wout, A2);
    // 2. in_proj (128x128 tiles), split epilogue: xs bf16 | zbuf fp32
    mfma_gemm128_split<<<dim3(1024/128, MM/128), 256, 0, stream>>>(xn, win, xs, zbuf, DIMC);
    // 3. conv + silu -> xu (bf16)
    conv_kernel<<<(MM*DIN)/256, 256, 0, stream>>>(xs, conv_w, conv_b, xu);
    // 4. x_proj: x_dbl = xu @ wxp^T  [4608,48]
    mfma_gemm<0><<<dim3(1, MM/64), 256, 0, stream>>>(xu, wxp, x_dbl, MM, 48, DIN, nullptr, nullptr, nullptr);
    // 5-7. chunked selective scan (dt_proj+softplus fused; gate fused in phase3)
    scan_phase1<<<(NC*NGRP)/256, 256, 0, stream>>>(xu, x_dbl, dt_proj_w, dt_proj_b, A2, aprod, hend);
    scan_phase2<<<NSEQ/256, 256, 0, stream>>>(aprod, hend, hin);
    scan_phase3<<<(NC*NGRP)/256, 256, 0, stream>>>(xu, x_dbl, dt_proj_w, dt_proj_b, A2, Dp, zbuf, hin, yg);
    // 8. out_proj + residual + transpose fused
    mfma_gemm<2><<<dim3(DIMC/64, MM/64), 256, 0, stream>>>(yg, wout, nullptr, MM, DIMC, DIN, x, gamma, out);
}